// Round 3
// baseline (252.340 us; speedup 1.0000x reference)
//
#include <hip/hip_runtime.h>

// ROI crop-and-resize, bilinear, half-pixel centers.
// fm: (64,64,128) fp32 NHWC; rois: (N,4) int32 [x1,y1,x2,y2]; out: (N,7,7,128) fp32.
// Write-bound floor ~38us (251 MB @ 6.7 TB/s measured fill rate).
// One block per ROI; half-wave (32 lanes) x float4 covers 128 channels of one
// (py,px) position = 512B coalesced store. Loop over positions FULLY UNROLLED
// (compile-time i, runtime posg) so up to 28 gathered loads are in flight ->
// hides L2 latency. Output stored nontemporal (write-once, keep fm in L2).

#define POOL 7
#define CH   128
#define FW   64

// native clang vector: __builtin_nontemporal_store rejects HIP_vector_type
typedef float nt_float4 __attribute__((ext_vector_type(4)));

__device__ __forceinline__ nt_float4 lerp4(nt_float4 a, nt_float4 b, float w) {
    return a + w * (b - a);   // element-wise, compiles to v_fma chains
}

__global__ __launch_bounds__(256) void roi_pool_kernel(
    const float* __restrict__ fm, const int* __restrict__ rois,
    float* __restrict__ out, int n_rois)
{
    const int n = blockIdx.x;

    const int4 r = ((const int4*)rois)[n];
    const int rx1 = r.x, ry1 = r.y, rx2 = r.z, ry2 = r.w;

    const int tid  = threadIdx.x;
    const int posg = tid >> 5;        // 0..7: position group
    const int lane = tid & 31;        // 0..31: channel group (float4)
    const int c    = lane << 2;

    nt_float4* outv = (nt_float4*)(out + (size_t)n * (POOL * POOL * CH));

    if ((rx1 | ry1 | rx2 | ry2) == 0) {
        // reference: all-zero roi -> zero output
        const nt_float4 z = (nt_float4)0.0f;
#pragma unroll
        for (int i = 0; i < 7; ++i) {
            const int pos = posg + (i << 3);
            if (pos < 49) __builtin_nontemporal_store(z, &outv[pos * 32 + lane]);
        }
        return;
    }

    const int hh = max(ry2 - ry1, 1);
    const int ww = max(rx2 - rx1, 1);
    const float hf = (float)hh;
    const float wf = (float)ww;
    const float hs = hf * (1.0f / 7.0f);
    const float ws7 = wf * (1.0f / 7.0f);

    const float* fmb = fm + c;   // channel-group base

#pragma unroll
    for (int i = 0; i < 7; ++i) {
        const int pos = posg + (i << 3);
        if (pos < 49) {
            // pos/7, pos%7 without magic-mul: (posg+8i) = 7i + (posg+i)
            const int s    = posg + i;          // 0..13
            const int over = (s >= 7) ? 1 : 0;
            const int py   = i + over;
            const int px   = s - over * 7;

            float yc = fminf(fmaxf((float)py * hs + (0.5f * hs - 0.5f), 0.0f), hf - 1.0f);
            float xc = fminf(fmaxf((float)px * ws7 + (0.5f * ws7 - 0.5f), 0.0f), wf - 1.0f);

            const int y0 = (int)yc;             // yc >= 0 -> trunc == floor
            const int x0 = (int)xc;
            const int y1 = min(y0 + 1, hh - 1);
            const int x1 = min(x0 + 1, ww - 1);
            const float wy = yc - (float)y0;
            const float wx = xc - (float)x0;

            const int row0 = (y0 + ry1) << 6;   // * FW
            const int row1 = (y1 + ry1) << 6;
            const int xa0  = x0 + rx1;
            const int xa1  = x1 + rx1;

            const nt_float4 g00 = *(const nt_float4*)(fmb + ((row0 + xa0) << 7));
            const nt_float4 g01 = *(const nt_float4*)(fmb + ((row0 + xa1) << 7));
            const nt_float4 g10 = *(const nt_float4*)(fmb + ((row1 + xa0) << 7));
            const nt_float4 g11 = *(const nt_float4*)(fmb + ((row1 + xa1) << 7));

            const nt_float4 top = lerp4(g00, g01, wx);
            const nt_float4 bot = lerp4(g10, g11, wx);
            const nt_float4 res = lerp4(top, bot, wy);

            __builtin_nontemporal_store(res, &outv[pos * 32 + lane]);
        }
    }
}

extern "C" void kernel_launch(void* const* d_in, const int* in_sizes, int n_in,
                              void* d_out, int out_size, void* d_ws, size_t ws_size,
                              hipStream_t stream) {
    const float* fm   = (const float*)d_in[0];
    const int*   rois = (const int*)d_in[1];
    float*       out  = (float*)d_out;
    const int n_rois  = in_sizes[1] / 4;  // (1, N, 4) int32

    roi_pool_kernel<<<n_rois, 256, 0, stream>>>(fm, rois, out, n_rois);
}